// Round 7
// baseline (1775.956 us; speedup 1.0000x reference)
//
#include <hip/hip_runtime.h>
#include <hip/hip_bf16.h>

#define NND 100000
#define NED 3200000
#define F 256
#define NCLS 64
#define NBIN 1563            // ceil(NND / 64) dst-bins of 64 nodes

typedef _Float16 f16x8 __attribute__((ext_vector_type(8)));
typedef _Float16 f16x4 __attribute__((ext_vector_type(4)));
typedef float f32x4 __attribute__((ext_vector_type(4)));

// ---------------- pass 1: bin histogram (bin = dst >> 6) ----------------
__global__ __launch_bounds__(256) void k_binhist(const int* __restrict__ dst, int* __restrict__ bh) {
    int i = blockIdx.x * 256 + threadIdx.x;
    if (i < NED) atomicAdd(&bh[dst[i] >> 6], 1);
}

// ---------------- pass 2: exclusive scan of bin counts (single block) ----------------
__global__ __launch_bounds__(256) void k_scanbin(const int* __restrict__ bh, int* __restrict__ bs,
                                                 int* __restrict__ cur, int n) {
    __shared__ int sh[256];
    __shared__ int carry;
    if (threadIdx.x == 0) carry = 0;
    __syncthreads();
    for (int base = 0; base < n; base += 256) {
        int i = base + threadIdx.x;
        int v = (i < n) ? bh[i] : 0;
        sh[threadIdx.x] = v;
        __syncthreads();
        for (int off = 1; off < 256; off <<= 1) {
            int tv = (threadIdx.x >= off) ? sh[threadIdx.x - off] : 0;
            __syncthreads();
            sh[threadIdx.x] += tv;
            __syncthreads();
        }
        if (i < n) {
            int ex = carry + sh[threadIdx.x] - v;
            bs[i] = ex;
            cur[i] = ex;
        }
        __syncthreads();
        if (threadIdx.x == 255) carry += sh[255];
        __syncthreads();
    }
    if (threadIdx.x == 0) bs[n] = carry;   // == NED
}

// ---------------- pass 3: scatter (src,dst) pairs into bin regions ----------------
// Only ~1563 write tails active -> lines stay hot in L2, no write amplification.
__global__ __launch_bounds__(256) void k_binfill(const int* __restrict__ src, const int* __restrict__ dst,
                                                 int* __restrict__ cur, int2* __restrict__ binned) {
    int i = blockIdx.x * 256 + threadIdx.x;
    if (i < NED) {
        int d = dst[i];
        int p = atomicAdd(&cur[d >> 6], 1);
        binned[p] = make_int2(src[i], d);
    }
}

// ---------------- pass 4: per-bin local CSR build (one block per bin) ----------------
__global__ __launch_bounds__(256) void k_bin2csr(const int2* __restrict__ binned,
                                                 const int* __restrict__ binstart,
                                                 int* __restrict__ deg, int* __restrict__ start,
                                                 float* __restrict__ norm, int* __restrict__ col) {
    __shared__ int h[64], lofs[64], cur[64];
    int b = blockIdx.x;
    int t = threadIdx.x;
    int n0 = b * 64;
    int e0 = binstart[b], e1 = binstart[b + 1];
    if (t < 64) h[t] = 0;
    __syncthreads();
    for (int i = e0 + t; i < e1; i += 256)
        atomicAdd(&h[binned[i].y - n0], 1);
    __syncthreads();
    if (t == 0) {
        int run = 0;
        for (int k = 0; k < 64; k++) { lofs[k] = run; cur[k] = run; run += h[k]; }
    }
    __syncthreads();
    if (t < 64 && n0 + t < NND) {
        int d = h[t];
        deg[n0 + t] = d;
        start[n0 + t] = e0 + lofs[t];
        float df = (float)d;
        norm[n0 + t] = rsqrtf(df < 1.0f ? 1.0f : df);
    }
    for (int i = e0 + t; i < e1; i += 256) {
        int2 e = binned[i];
        int r = atomicAdd(&cur[e.y - n0], 1);
        col[e0 + r] = e.x;
    }
}

// ---------------- LayerNorm (one wave per node) -> pre-scaled fp16 (norm * LN) ----------------
__global__ __launch_bounds__(256) void k_ln(const float* __restrict__ x, const float* __restrict__ gamma,
                                            const float* __restrict__ beta, const float* __restrict__ norm,
                                            _Float16* __restrict__ y) {
    int node = blockIdx.x * 4 + (threadIdx.x >> 6);
    int lane = threadIdx.x & 63;
    if (node >= NND) return;
    float4 v = ((const float4*)x)[node * 64 + lane];
    float s = v.x + v.y + v.z + v.w;
    float s2 = v.x * v.x + v.y * v.y + v.z * v.z + v.w * v.w;
    for (int m = 1; m < 64; m <<= 1) {
        s += __shfl_xor(s, m, 64);
        s2 += __shfl_xor(s2, m, 64);
    }
    float mu = s * (1.0f / 256.0f);
    float var = s2 * (1.0f / 256.0f) - mu * mu;
    float rs = rsqrtf(var + 1e-5f);
    float w = norm[node];
    float4 g = ((const float4*)gamma)[lane];
    float4 b = ((const float4*)beta)[lane];
    f16x4 o;
    o[0] = (_Float16)(w * ((v.x - mu) * rs * g.x + b.x));
    o[1] = (_Float16)(w * ((v.y - mu) * rs * g.y + b.y));
    o[2] = (_Float16)(w * ((v.z - mu) * rs * g.z + b.z));
    o[3] = (_Float16)(w * ((v.w - mu) * rs * g.w + b.w));
    *(f16x4*)(y + (size_t)node * F + lane * 4) = o;
}

// ---------------- one propagation hop (round-3 proven version) ----------------
// x pre-scaled by norm. LAST=0: write norm^2 * sum. LAST=1: write norm * sum.
template <int LAST>
__global__ __launch_bounds__(256) void k_hop(const _Float16* __restrict__ x, _Float16* __restrict__ y,
                                             const int* __restrict__ start, const int* __restrict__ deg,
                                             const int* __restrict__ col, const float* __restrict__ norm) {
    int node = __builtin_amdgcn_readfirstlane(blockIdx.x * 4 + (threadIdx.x >> 6));
    if (node >= NND) return;
    int lane = threadIdx.x & 63;
    int hf = lane >> 5;       // which edge of the pair
    int l = lane & 31;        // 32 lanes x 8 halfs = 256 feats
    int s0 = start[node];
    int cnt = deg[node];
    float acc[8] = {0.f, 0.f, 0.f, 0.f, 0.f, 0.f, 0.f, 0.f};
    for (int base = 0; base < cnt; base += 64) {
        int rem = cnt - base;
        int cv = (lane < rem) ? col[s0 + base + lane] : 0;
        int npair = rem > 64 ? 32 : (rem >> 1);
#pragma unroll 2
        for (int i = 0; i < npair; i++) {
            int s = __shfl(cv, 2 * i + hf, 64);
            f16x8 v = *(const f16x8*)(x + (size_t)s * F + l * 8);
#pragma unroll
            for (int j = 0; j < 8; j++) acc[j] += (float)v[j];
        }
        if ((rem & 1) && rem <= 64) {   // odd leftover edge in final chunk
            int s = __shfl(cv, rem - 1, 64);
            if (hf == 0) {
                f16x8 v = *(const f16x8*)(x + (size_t)s * F + l * 8);
#pragma unroll
                for (int j = 0; j < 8; j++) acc[j] += (float)v[j];
            }
        }
    }
#pragma unroll
    for (int j = 0; j < 8; j++) acc[j] += __shfl_xor(acc[j], 32, 64);
    if (hf == 0) {
        float wd = norm[node];
        float sc = LAST ? wd : wd * wd;
        f16x8 o;
#pragma unroll
        for (int j = 0; j < 8; j++) o[j] = (_Float16)(acc[j] * sc);
        *(f16x8*)(y + (size_t)node * F + (size_t)l * 8) = o;
    }
}

// ---------------- fp32 -> fp16 cast of both weight matrices (one launch) ----------------
__global__ __launch_bounds__(256) void k_castW(const float4* __restrict__ Wc, const float4* __restrict__ Wf,
                                               f16x4* __restrict__ WcO, f16x4* __restrict__ WfO) {
    int i = blockIdx.x * 256 + threadIdx.x;
    if (i < F * F / 4) {
        float4 v = Wc[i];
        f16x4 o;
        o[0] = (_Float16)v.x; o[1] = (_Float16)v.y; o[2] = (_Float16)v.z; o[3] = (_Float16)v.w;
        WcO[i] = o;
    } else {
        int j = i - F * F / 4;
        if (j < NCLS * F / 4) {
            float4 v = Wf[j];
            f16x4 o;
            o[0] = (_Float16)v.x; o[1] = (_Float16)v.y; o[2] = (_Float16)v.z; o[3] = (_Float16)v.w;
            WfO[j] = o;
        }
    }
}

// ---------------- fused GEMM: relu(h3 @ Wc^T + bc) @ Wf^T + bf ----------------
__global__ __launch_bounds__(256) void k_gemm(const _Float16* __restrict__ A,
                                              const _Float16* __restrict__ Wc, const float* __restrict__ bc,
                                              const _Float16* __restrict__ Wf, const float* __restrict__ bf,
                                              float* __restrict__ out) {
    __shared__ _Float16 mid[16][264];   // +8 pad kills bank conflicts
    int wave = threadIdx.x >> 6, lane = threadIdx.x & 63;
    int l15 = lane & 15, lhi = lane >> 4;
    int row0 = blockIdx.x * 16;
    const _Float16* arow = A + (size_t)(row0 + l15) * F + lhi * 8;
    int ncol0 = wave * 64;
    f32x4 acc[4];
    for (int t = 0; t < 4; t++) acc[t] = (f32x4){0.f, 0.f, 0.f, 0.f};
#pragma unroll
    for (int kt = 0; kt < 8; kt++) {
        f16x8 a = *(const f16x8*)(arow + kt * 32);
#pragma unroll
        for (int t = 0; t < 4; t++) {
            int n = ncol0 + t * 16 + l15;
            f16x8 b = *(const f16x8*)(Wc + (size_t)n * F + lhi * 8 + kt * 32);
            acc[t] = __builtin_amdgcn_mfma_f32_16x16x32_f16(a, b, acc[t], 0, 0, 0);
        }
    }
#pragma unroll
    for (int t = 0; t < 4; t++) {
        int colb = ncol0 + t * 16 + l15;
        float bv = bc[colb];
#pragma unroll
        for (int r = 0; r < 4; r++) {
            float v = acc[t][r] + bv;
            mid[lhi * 4 + r][colb] = (_Float16)(v > 0.f ? v : 0.f);
        }
    }
    __syncthreads();
    f32x4 acc2 = (f32x4){0.f, 0.f, 0.f, 0.f};
    int colb = wave * 16 + l15;
    const _Float16* brow = Wf + (size_t)colb * F + lhi * 8;
#pragma unroll
    for (int kt = 0; kt < 8; kt++) {
        f16x8 a = *(const f16x8*)&mid[l15][lhi * 8 + kt * 32];
        f16x8 b = *(const f16x8*)(brow + kt * 32);
        acc2 = __builtin_amdgcn_mfma_f32_16x16x32_f16(a, b, acc2, 0, 0, 0);
    }
    float bv = bf[colb];
#pragma unroll
    for (int r = 0; r < 4; r++) {
        int row = row0 + lhi * 4 + r;
        out[(size_t)row * NCLS + colb] = acc2[r] + bv;
    }
}

extern "C" void kernel_launch(void* const* d_in, const int* in_sizes, int n_in,
                              void* d_out, int out_size, void* d_ws, size_t ws_size,
                              hipStream_t stream) {
    const float* features = (const float*)d_in[0];
    const int* edge_src = (const int*)d_in[1];
    const int* edge_dst = (const int*)d_in[2];
    const float* ln_gamma = (const float*)d_in[3];
    const float* ln_beta = (const float*)d_in[4];
    const float* W_conv = (const float*)d_in[5];
    const float* b_conv = (const float*)d_in[6];
    const float* W_fc = (const float*)d_in[7];
    const float* b_fc = (const float*)d_in[8];
    float* out = (float*)d_out;

    char* w = (char*)d_ws;
    const size_t HB2 = (size_t)NND * F * 2;            // 51,200,000 (fp16 h)
    _Float16* hA = (_Float16*)(w + 0);
    _Float16* hB = (_Float16*)(w + HB2);
    int* col = (int*)(w + 102400000);                  // 12.8 MB
    int2* binned = (int2*)(w + 115200000);             // 25.6 MB
    int* deg = (int*)(w + 140800000);                  // 400 KB
    int* start = (int*)(w + 141200000);                // 400 KB
    float* norm = (float*)(w + 141600000);             // 400 KB
    int* binhist = (int*)(w + 142000000);              // NBIN
    int* bincur = (int*)(w + 142008192);               // NBIN
    int* binstart = (int*)(w + 142016384);             // NBIN+1
    _Float16* Wc16 = (_Float16*)(w + 142032768);
    _Float16* Wf16 = (_Float16*)(w + 142163840);

    hipMemsetAsync(binhist, 0, NBIN * sizeof(int), stream);

    const int EB = (NED + 255) / 256;   // 12500

    k_binhist<<<EB, 256, 0, stream>>>(edge_dst, binhist);
    k_scanbin<<<1, 256, 0, stream>>>(binhist, binstart, bincur, NBIN);
    k_binfill<<<EB, 256, 0, stream>>>(edge_src, edge_dst, bincur, binned);
    k_bin2csr<<<NBIN, 256, 0, stream>>>(binned, binstart, deg, start, norm, col);

    k_ln<<<NND / 4, 256, 0, stream>>>(features, ln_gamma, ln_beta, norm, hA);

    k_hop<0><<<NND / 4, 256, 0, stream>>>(hA, hB, start, deg, col, norm);
    k_hop<0><<<NND / 4, 256, 0, stream>>>(hB, hA, start, deg, col, norm);
    k_hop<1><<<NND / 4, 256, 0, stream>>>(hA, hB, start, deg, col, norm);

    k_castW<<<(F * F / 4 + NCLS * F / 4 + 255) / 256, 256, 0, stream>>>(
        (const float4*)W_conv, (const float4*)W_fc, (f16x4*)Wc16, (f16x4*)Wf16);

    k_gemm<<<NND / 16, 256, 0, stream>>>(hB, Wc16, b_conv, Wf16, b_fc, out);
}

// Round 8
// 889.997 us; speedup vs baseline: 1.9955x; 1.9955x over previous
//
#include <hip/hip_runtime.h>
#include <hip/hip_bf16.h>

#define NND 100000
#define NED 3200000
#define F 256
#define NCLS 64
#define NC 98                // coarse buckets (dst >> 10)
#define MAXPER 36864         // slack per bucket (mean 32768, sigma ~181)
#define EBLK 4096            // edges per pass-A block

typedef _Float16 f16x8 __attribute__((ext_vector_type(8)));
typedef _Float16 f16x4 __attribute__((ext_vector_type(4)));
typedef float f32x4 __attribute__((ext_vector_type(4)));

// ---------------- init per-bucket global cursors ----------------
__global__ void k_init(int* __restrict__ gcur) {
    int b = threadIdx.x;
    if (b < NC) gcur[b] = b * MAXPER;
}

// ---------------- pass A: block-aggregated coarse binning, coalesced flush ----------------
__global__ __launch_bounds__(256) void k_passA(const int* __restrict__ src, const int* __restrict__ dst,
                                               int* __restrict__ gcur, int2* __restrict__ binned) {
    __shared__ int hist[NC], scn[NC], cur[NC], gbase[NC];
    __shared__ int2 stage[EBLK];
    __shared__ unsigned char bkt[EBLK];
    int base = blockIdx.x * EBLK;
    int n = NED - base; if (n > EBLK) n = EBLK;
    int t = threadIdx.x;
    if (t < NC) hist[t] = 0;
    __syncthreads();
    for (int i = t; i < n; i += 256) atomicAdd(&hist[dst[base + i] >> 10], 1);
    __syncthreads();
    if (t == 0) {
        int run = 0;
        for (int b = 0; b < NC; b++) { scn[b] = run; cur[b] = run; run += hist[b]; }
    }
    __syncthreads();
    if (t < NC) gbase[t] = atomicAdd(&gcur[t], hist[t]);   // one global atomic per (block,bucket)
    __syncthreads();
    for (int i = t; i < n; i += 256) {
        int s = src[base + i], d = dst[base + i];
        int b = d >> 10;
        int r = atomicAdd(&cur[b], 1);
        stage[r] = make_int2(s, d);
        bkt[r] = (unsigned char)b;
    }
    __syncthreads();
    for (int i = t; i < n; i += 256) {
        int b = bkt[i];
        binned[gbase[b] + (i - scn[b])] = stage[i];        // contiguous runs per bucket
    }
}

// ---------------- tiny scan: col base per bucket ----------------
__global__ void k_cscan(const int* __restrict__ gcur, int* __restrict__ cbase) {
    if (threadIdx.x == 0) {
        int run = 0;
        for (int b = 0; b < NC; b++) { cbase[b] = run; run += gcur[b] - b * MAXPER; }
        cbase[NC] = run;
    }
}

// ---------------- pass B: per-bucket local CSR (LDS hist + scan + rank scatter) ----------------
__global__ __launch_bounds__(1024) void k_passB(const int2* __restrict__ binned, const int* __restrict__ cbase,
                                                int* __restrict__ deg, int* __restrict__ start,
                                                float* __restrict__ norm, int* __restrict__ col) {
    __shared__ int h[1024], sh[1024], cur[1024];
    int b = blockIdx.x;
    int t = threadIdx.x;
    int n0 = b << 10;
    const int2* eb = binned + (size_t)b * MAXPER;
    int c0 = cbase[b];
    int cnt = cbase[b + 1] - c0;
    h[t] = 0;
    __syncthreads();
    for (int i = t; i < cnt; i += 1024) atomicAdd(&h[eb[i].y - n0], 1);
    __syncthreads();
    sh[t] = h[t];
    __syncthreads();
    for (int off = 1; off < 1024; off <<= 1) {
        int v = (t >= off) ? sh[t - off] : 0;
        __syncthreads();
        sh[t] += v;
        __syncthreads();
    }
    int lofs = sh[t] - h[t];
    cur[t] = lofs;
    int node = n0 + t;
    if (node < NND) {
        int d = h[t];
        deg[node] = d;
        start[node] = c0 + lofs;
        float df = (float)d;
        norm[node] = rsqrtf(df < 1.0f ? 1.0f : df);
    }
    __syncthreads();
    for (int i = t; i < cnt; i += 1024) {
        int2 e = eb[i];
        int r = atomicAdd(&cur[e.y - n0], 1);
        col[c0 + r] = e.x;                                 // scatter within L2-resident ~130KB region
    }
}

// ---------------- LayerNorm (one wave per node) -> pre-scaled fp16 (norm * LN) ----------------
__global__ __launch_bounds__(256) void k_ln(const float* __restrict__ x, const float* __restrict__ gamma,
                                            const float* __restrict__ beta, const float* __restrict__ norm,
                                            _Float16* __restrict__ y) {
    int node = blockIdx.x * 4 + (threadIdx.x >> 6);
    int lane = threadIdx.x & 63;
    if (node >= NND) return;
    float4 v = ((const float4*)x)[node * 64 + lane];
    float s = v.x + v.y + v.z + v.w;
    float s2 = v.x * v.x + v.y * v.y + v.z * v.z + v.w * v.w;
    for (int m = 1; m < 64; m <<= 1) {
        s += __shfl_xor(s, m, 64);
        s2 += __shfl_xor(s2, m, 64);
    }
    float mu = s * (1.0f / 256.0f);
    float var = s2 * (1.0f / 256.0f) - mu * mu;
    float rs = rsqrtf(var + 1e-5f);
    float w = norm[node];
    float4 g = ((const float4*)gamma)[lane];
    float4 b = ((const float4*)beta)[lane];
    f16x4 o;
    o[0] = (_Float16)(w * ((v.x - mu) * rs * g.x + b.x));
    o[1] = (_Float16)(w * ((v.y - mu) * rs * g.y + b.y));
    o[2] = (_Float16)(w * ((v.z - mu) * rs * g.z + b.z));
    o[3] = (_Float16)(w * ((v.w - mu) * rs * g.w + b.w));
    *(f16x4*)(y + (size_t)node * F + lane * 4) = o;
}

// ---------------- one propagation hop (round-3 proven version) ----------------
template <int LAST>
__global__ __launch_bounds__(256) void k_hop(const _Float16* __restrict__ x, _Float16* __restrict__ y,
                                             const int* __restrict__ start, const int* __restrict__ deg,
                                             const int* __restrict__ col, const float* __restrict__ norm) {
    int node = __builtin_amdgcn_readfirstlane(blockIdx.x * 4 + (threadIdx.x >> 6));
    if (node >= NND) return;
    int lane = threadIdx.x & 63;
    int hf = lane >> 5;
    int l = lane & 31;
    int s0 = start[node];
    int cnt = deg[node];
    float acc[8] = {0.f, 0.f, 0.f, 0.f, 0.f, 0.f, 0.f, 0.f};
    for (int base = 0; base < cnt; base += 64) {
        int rem = cnt - base;
        int cv = (lane < rem) ? col[s0 + base + lane] : 0;
        int npair = rem > 64 ? 32 : (rem >> 1);
#pragma unroll 2
        for (int i = 0; i < npair; i++) {
            int s = __shfl(cv, 2 * i + hf, 64);
            f16x8 v = *(const f16x8*)(x + (size_t)s * F + l * 8);
#pragma unroll
            for (int j = 0; j < 8; j++) acc[j] += (float)v[j];
        }
        if ((rem & 1) && rem <= 64) {
            int s = __shfl(cv, rem - 1, 64);
            if (hf == 0) {
                f16x8 v = *(const f16x8*)(x + (size_t)s * F + l * 8);
#pragma unroll
                for (int j = 0; j < 8; j++) acc[j] += (float)v[j];
            }
        }
    }
#pragma unroll
    for (int j = 0; j < 8; j++) acc[j] += __shfl_xor(acc[j], 32, 64);
    if (hf == 0) {
        float wd = norm[node];
        float sc = LAST ? wd : wd * wd;
        f16x8 o;
#pragma unroll
        for (int j = 0; j < 8; j++) o[j] = (_Float16)(acc[j] * sc);
        *(f16x8*)(y + (size_t)node * F + (size_t)l * 8) = o;
    }
}

// ---------------- fp32 -> fp16 cast of both weight matrices ----------------
__global__ __launch_bounds__(256) void k_castW(const float4* __restrict__ Wc, const float4* __restrict__ Wf,
                                               f16x4* __restrict__ WcO, f16x4* __restrict__ WfO) {
    int i = blockIdx.x * 256 + threadIdx.x;
    if (i < F * F / 4) {
        float4 v = Wc[i];
        f16x4 o;
        o[0] = (_Float16)v.x; o[1] = (_Float16)v.y; o[2] = (_Float16)v.z; o[3] = (_Float16)v.w;
        WcO[i] = o;
    } else {
        int j = i - F * F / 4;
        if (j < NCLS * F / 4) {
            float4 v = Wf[j];
            f16x4 o;
            o[0] = (_Float16)v.x; o[1] = (_Float16)v.y; o[2] = (_Float16)v.z; o[3] = (_Float16)v.w;
            WfO[j] = o;
        }
    }
}

// ---------------- fused GEMM: relu(h3 @ Wc^T + bc) @ Wf^T + bf ----------------
__global__ __launch_bounds__(256) void k_gemm(const _Float16* __restrict__ A,
                                              const _Float16* __restrict__ Wc, const float* __restrict__ bc,
                                              const _Float16* __restrict__ Wf, const float* __restrict__ bf,
                                              float* __restrict__ out) {
    __shared__ _Float16 mid[16][264];
    int wave = threadIdx.x >> 6, lane = threadIdx.x & 63;
    int l15 = lane & 15, lhi = lane >> 4;
    int row0 = blockIdx.x * 16;
    const _Float16* arow = A + (size_t)(row0 + l15) * F + lhi * 8;
    int ncol0 = wave * 64;
    f32x4 acc[4];
    for (int t = 0; t < 4; t++) acc[t] = (f32x4){0.f, 0.f, 0.f, 0.f};
#pragma unroll
    for (int kt = 0; kt < 8; kt++) {
        f16x8 a = *(const f16x8*)(arow + kt * 32);
#pragma unroll
        for (int t = 0; t < 4; t++) {
            int n = ncol0 + t * 16 + l15;
            f16x8 b = *(const f16x8*)(Wc + (size_t)n * F + lhi * 8 + kt * 32);
            acc[t] = __builtin_amdgcn_mfma_f32_16x16x32_f16(a, b, acc[t], 0, 0, 0);
        }
    }
#pragma unroll
    for (int t = 0; t < 4; t++) {
        int colb = ncol0 + t * 16 + l15;
        float bv = bc[colb];
#pragma unroll
        for (int r = 0; r < 4; r++) {
            float v = acc[t][r] + bv;
            mid[lhi * 4 + r][colb] = (_Float16)(v > 0.f ? v : 0.f);
        }
    }
    __syncthreads();
    f32x4 acc2 = (f32x4){0.f, 0.f, 0.f, 0.f};
    int colb = wave * 16 + l15;
    const _Float16* brow = Wf + (size_t)colb * F + lhi * 8;
#pragma unroll
    for (int kt = 0; kt < 8; kt++) {
        f16x8 a = *(const f16x8*)&mid[l15][lhi * 8 + kt * 32];
        f16x8 b = *(const f16x8*)(brow + kt * 32);
        acc2 = __builtin_amdgcn_mfma_f32_16x16x32_f16(a, b, acc2, 0, 0, 0);
    }
    float bv = bf[colb];
#pragma unroll
    for (int r = 0; r < 4; r++) {
        int row = row0 + lhi * 4 + r;
        out[(size_t)row * NCLS + colb] = acc2[r] + bv;
    }
}

extern "C" void kernel_launch(void* const* d_in, const int* in_sizes, int n_in,
                              void* d_out, int out_size, void* d_ws, size_t ws_size,
                              hipStream_t stream) {
    const float* features = (const float*)d_in[0];
    const int* edge_src = (const int*)d_in[1];
    const int* edge_dst = (const int*)d_in[2];
    const float* ln_gamma = (const float*)d_in[3];
    const float* ln_beta = (const float*)d_in[4];
    const float* W_conv = (const float*)d_in[5];
    const float* b_conv = (const float*)d_in[6];
    const float* W_fc = (const float*)d_in[7];
    const float* b_fc = (const float*)d_in[8];
    float* out = (float*)d_out;

    char* w = (char*)d_ws;
    const size_t HB2 = (size_t)NND * F * 2;            // 51,200,000 (fp16 h)
    _Float16* hA = (_Float16*)(w + 0);
    int2* binned = (int2*)(w + 0);                     // 28.9 MB, aliases hA (dead before k_ln)
    _Float16* hB = (_Float16*)(w + HB2);
    int* col = (int*)(w + 102400000);                  // 12.8 MB
    int* deg = (int*)(w + 115200000);                  // 400 KB
    int* start = (int*)(w + 115600000);                // 400 KB
    float* norm = (float*)(w + 116000000);             // 400 KB
    int* gcur = (int*)(w + 116400000);                 // NC ints
    int* cbase = (int*)(w + 116401024);                // NC+1 ints
    _Float16* Wc16 = (_Float16*)(w + 116402176);
    _Float16* Wf16 = (_Float16*)(w + 116533248);

    k_init<<<1, 128, 0, stream>>>(gcur);
    k_passA<<<(NED + EBLK - 1) / EBLK, 256, 0, stream>>>(edge_src, edge_dst, gcur, binned);
    k_cscan<<<1, 64, 0, stream>>>(gcur, cbase);
    k_passB<<<NC, 1024, 0, stream>>>(binned, cbase, deg, start, norm, col);

    k_ln<<<NND / 4, 256, 0, stream>>>(features, ln_gamma, ln_beta, norm, hA);

    k_hop<0><<<NND / 4, 256, 0, stream>>>(hA, hB, start, deg, col, norm);
    k_hop<0><<<NND / 4, 256, 0, stream>>>(hB, hA, start, deg, col, norm);
    k_hop<1><<<NND / 4, 256, 0, stream>>>(hA, hB, start, deg, col, norm);

    k_castW<<<(F * F / 4 + NCLS * F / 4 + 255) / 256, 256, 0, stream>>>(
        (const float4*)W_conv, (const float4*)W_fc, (f16x4*)Wc16, (f16x4*)Wf16);

    k_gemm<<<NND / 16, 256, 0, stream>>>(hB, Wc16, b_conv, Wf16, b_fc, out);
}